// Round 1
// baseline (2009.251 us; speedup 1.0000x reference)
//
#include <hip/hip_runtime.h>
#include <math.h>

#define S 4096
#define CIN 256
#define C3 768
#define NH 8
#define HD 32

static constexpr float EPS = 1e-4f;

// ---------------- weight norm: W_eff = w / (||row|| + 16*EPS) ----------------
__global__ __launch_bounds__(256) void wnorm_kernel(const float* __restrict__ w,
                                                    float* __restrict__ wh) {
  const int row = blockIdx.x * 4 + (threadIdx.x >> 6);
  const int lane = threadIdx.x & 63;
  const float* wr = w + (size_t)row * CIN;
  float v0 = wr[lane], v1 = wr[lane + 64], v2 = wr[lane + 128], v3 = wr[lane + 192];
  float ss = v0 * v0 + v1 * v1 + v2 * v2 + v3 * v3;
  #pragma unroll
  for (int off = 32; off > 0; off >>= 1) ss += __shfl_down(ss, off, 64);
  ss = __shfl(ss, 0, 64);
  const float scale = 1.0f / (sqrtf(ss) + 16.0f * EPS);
  float* whr = wh + (size_t)row * CIN;
  whr[lane] = v0 * scale;
  whr[lane + 64] = v1 * scale;
  whr[lane + 128] = v2 * scale;
  whr[lane + 192] = v3 * scale;
}

// ---------------- 1x1 conv = channel GEMM: OUT[b,o,s] = sum_c W[o,c] X[b,c,s] ----------------
// grid (S/64, OC/64, B), block 256. 64x64 tile, 4x4 per thread, K-tile 16.
template <int OC, bool FUSE>
__global__ __launch_bounds__(256) void conv1x1_kernel(const float* __restrict__ W,
                                                      const float* __restrict__ X,
                                                      float* __restrict__ OUT,
                                                      const float* __restrict__ RES) {
  const int b = blockIdx.z;
  const int o0 = blockIdx.y * 64;
  const int s0 = blockIdx.x * 64;
  const int t = threadIdx.x;
  const int tx = t & 15, ty = t >> 4;
  __shared__ float Ws[16][64];
  __shared__ float Xs[16][64];
  float acc[4][4] = {};

  const int wrow = t & 63;       // o index for W loads
  const int wk0 = (t >> 6) * 4;  // c offset for W loads (float4 along c)
  const int xk = t >> 4;         // c row for X loads (0..15)
  const int xs0 = (t & 15) * 4;  // s offset for X loads (float4 along s)
  const float* Xb = X + (size_t)b * CIN * S;

  for (int c0 = 0; c0 < CIN; c0 += 16) {
    __syncthreads();
    float4 wv = *(const float4*)&W[(size_t)(o0 + wrow) * CIN + c0 + wk0];
    Ws[wk0 + 0][wrow] = wv.x;
    Ws[wk0 + 1][wrow] = wv.y;
    Ws[wk0 + 2][wrow] = wv.z;
    Ws[wk0 + 3][wrow] = wv.w;
    *(float4*)&Xs[xk][xs0] = *(const float4*)&Xb[(size_t)(c0 + xk) * S + s0 + xs0];
    __syncthreads();
    #pragma unroll
    for (int kk = 0; kk < 16; kk++) {
      float4 a = *(const float4*)&Ws[kk][ty * 4];
      float4 xv = *(const float4*)&Xs[kk][tx * 4];
      acc[0][0] += a.x * xv.x; acc[0][1] += a.x * xv.y; acc[0][2] += a.x * xv.z; acc[0][3] += a.x * xv.w;
      acc[1][0] += a.y * xv.x; acc[1][1] += a.y * xv.y; acc[1][2] += a.y * xv.z; acc[1][3] += a.y * xv.w;
      acc[2][0] += a.z * xv.x; acc[2][1] += a.z * xv.y; acc[2][2] += a.z * xv.z; acc[2][3] += a.z * xv.w;
      acc[3][0] += a.w * xv.x; acc[3][1] += a.w * xv.y; acc[3][2] += a.w * xv.z; acc[3][3] += a.w * xv.w;
    }
  }
  #pragma unroll
  for (int i = 0; i < 4; i++) {
    const size_t idx = ((size_t)b * OC + o0 + ty * 4 + i) * S + s0 + tx * 4;
    float4 r = make_float4(acc[i][0], acc[i][1], acc[i][2], acc[i][3]);
    if (FUSE) {
      // mp_add(x, y, t=0.3): ((1-t)x + t*y) / sqrt(t^2 + (1-t)^2)
      const float4 xr = *(const float4*)&RES[idx];
      const float tc = 0.3f, om = 0.7f, inv = 1.3130643285972254f;
      r.x = (om * xr.x + tc * r.x) * inv;
      r.y = (om * xr.y + tc * r.y) * inv;
      r.z = (om * xr.z + tc * r.z) * inv;
      r.w = (om * xr.w + tc * r.w) * inv;
    }
    *(float4*)&OUT[idx] = r;
  }
}

// ---------------- pixel norm over 32-channel head groups ----------------
// grid (S/256, 24, B), block 256
__global__ __launch_bounds__(256) void pixnorm_kernel(float* __restrict__ qkv) {
  const int b = blockIdx.z, g = blockIdx.y;
  const int s = blockIdx.x * 256 + threadIdx.x;
  const size_t base = ((size_t)b * C3 + g * HD) * S + s;
  float v[HD];
  float ss = 0.f;
  #pragma unroll
  for (int d = 0; d < HD; d++) {
    v[d] = qkv[base + (size_t)d * S];
    ss += v[d] * v[d];
  }
  const float r = rsqrtf(ss * (1.0f / HD) + EPS);
  #pragma unroll
  for (int d = 0; d < HD; d++) qkv[base + (size_t)d * S] = v[d] * r;
}

// ---------------- attention ----------------
// Cosine attention: |scores| <= sqrt(32) so exp() never overflows -> no online max.
// One query row per lane (q, acc in VGPRs). K/V tiles (64 keys) staged in LDS,
// stride 36 keeps float4 rows 16B-aligned and caps write conflicts at 8-way.
// grid (S/256, NH, B), block 256.
__global__ __launch_bounds__(256) void attn_kernel(const float* __restrict__ qkv,
                                                   float* __restrict__ y) {
  const int b = blockIdx.z, h = blockIdx.y;
  const int sq = blockIdx.x * 256 + threadIdx.x;
  const float* Q = qkv + ((size_t)b * C3 + h * HD) * S;
  const float* K = qkv + ((size_t)b * C3 + CIN + h * HD) * S;
  const float* V = qkv + ((size_t)b * C3 + 2 * CIN + h * HD) * S;
  float q[HD], acc[HD];
  #pragma unroll
  for (int d = 0; d < HD; d++) {
    q[d] = Q[(size_t)d * S + sq];
    acc[d] = 0.f;
  }
  float l = 0.f;
  const float scale = 0.17677669529663687f;  // 1/sqrt(32)
  __shared__ __align__(16) float Ks[64][36];
  __shared__ __align__(16) float Vs[64][36];

  for (int kt = 0; kt < S; kt += 64) {
    __syncthreads();
    #pragma unroll
    for (int i = 0; i < 8; i++) {
      const int e = threadIdx.x + i * 256;
      const int kr = e & 63, d = e >> 6;
      Ks[kr][d] = K[(size_t)d * S + kt + kr];
      Vs[kr][d] = V[(size_t)d * S + kt + kr];
    }
    __syncthreads();
    #pragma unroll 4
    for (int k = 0; k < 64; k++) {
      const float4* kp = (const float4*)&Ks[k][0];
      float s = 0.f;
      #pragma unroll
      for (int g = 0; g < 8; g++) {
        const float4 kv = kp[g];
        s += q[4 * g + 0] * kv.x + q[4 * g + 1] * kv.y +
             q[4 * g + 2] * kv.z + q[4 * g + 3] * kv.w;
      }
      const float p = __expf(s * scale);
      l += p;
      const float4* vp = (const float4*)&Vs[k][0];
      #pragma unroll
      for (int g = 0; g < 8; g++) {
        const float4 vv = vp[g];
        acc[4 * g + 0] += p * vv.x;
        acc[4 * g + 1] += p * vv.y;
        acc[4 * g + 2] += p * vv.z;
        acc[4 * g + 3] += p * vv.w;
      }
    }
  }
  const float inv_l = 1.0f / l;
  float* Y = y + ((size_t)b * CIN + h * HD) * S;
  #pragma unroll
  for (int d = 0; d < HD; d++) Y[(size_t)d * S + sq] = acc[d] * inv_l;
}

// ---------------- launch ----------------
extern "C" void kernel_launch(void* const* d_in, const int* in_sizes, int n_in,
                              void* d_out, int out_size, void* d_ws, size_t ws_size,
                              hipStream_t stream) {
  const float* x = (const float*)d_in[0];       // [2,256,64,64]
  const float* w_qkv = (const float*)d_in[1];   // [768,256]
  const float* w_out = (const float*)d_in[2];   // [256,256]
  float* out = (float*)d_out;                   // [2,256,64,64]

  float* ws = (float*)d_ws;
  float* wq_hat = ws;                                  // 768*256
  float* wo_hat = wq_hat + (size_t)C3 * CIN;           // 256*256
  float* qkv = wo_hat + (size_t)CIN * CIN;             // 2*768*4096
  float* ybuf = qkv + (size_t)2 * C3 * S;              // 2*256*4096

  wnorm_kernel<<<C3 / 4, 256, 0, stream>>>(w_qkv, wq_hat);
  wnorm_kernel<<<CIN / 4, 256, 0, stream>>>(w_out, wo_hat);
  conv1x1_kernel<C3, false><<<dim3(S / 64, C3 / 64, 2), 256, 0, stream>>>(wq_hat, x, qkv, nullptr);
  pixnorm_kernel<<<dim3(S / 256, C3 / HD, 2), 256, 0, stream>>>(qkv);
  attn_kernel<<<dim3(S / 256, NH, 2), 256, 0, stream>>>(qkv, ybuf);
  conv1x1_kernel<CIN, true><<<dim3(S / 64, CIN / 64, 2), 256, 0, stream>>>(wo_hat, ybuf, out, x);
}

// Round 2
// 228.747 us; speedup vs baseline: 8.7837x; 8.7837x over previous
//
#include <hip/hip_runtime.h>
#include <hip/hip_bf16.h>
#include <math.h>

#define S 4096
#define CIN 256
#define C3 768
#define NH 8
#define HD 32

static constexpr float EPS = 1e-4f;

typedef __attribute__((ext_vector_type(8))) __bf16 bf16x8;
typedef __attribute__((ext_vector_type(4))) float f32x4;

static inline __device__ ushort f2bf(float f) {
  unsigned u = __float_as_uint(f);
  unsigned r = (u + 0x7fffu + ((u >> 16) & 1u)) >> 16;
  return (ushort)r;
}
static inline __device__ float bf2f(ushort u) {
  return __uint_as_float(((unsigned)u) << 16);
}

// ---------------- weight norm: W_eff = w / (||row|| + 16*EPS) ----------------
__global__ __launch_bounds__(256) void wnorm_kernel(const float* __restrict__ w,
                                                    float* __restrict__ wh) {
  const int row = blockIdx.x * 4 + (threadIdx.x >> 6);
  const int lane = threadIdx.x & 63;
  const float* wr = w + (size_t)row * CIN;
  float v0 = wr[lane], v1 = wr[lane + 64], v2 = wr[lane + 128], v3 = wr[lane + 192];
  float ss = v0 * v0 + v1 * v1 + v2 * v2 + v3 * v3;
  #pragma unroll
  for (int off = 32; off > 0; off >>= 1) ss += __shfl_down(ss, off, 64);
  ss = __shfl(ss, 0, 64);
  const float scale = 1.0f / (sqrtf(ss) + 16.0f * EPS);
  float* whr = wh + (size_t)row * CIN;
  whr[lane] = v0 * scale;
  whr[lane + 64] = v1 * scale;
  whr[lane + 128] = v2 * scale;
  whr[lane + 192] = v3 * scale;
}

// ---------------- 1x1 conv = channel GEMM: OUT[b,o,s] = sum_c W[o,c] X[b,c,s] ---
// MODE 0: write bf16 (OUT is ushort*). MODE 1: write float with mp_add fuse.
template <int OC, int MODE>
__global__ __launch_bounds__(256) void conv1x1_kernel(const float* __restrict__ W,
                                                      const float* __restrict__ X,
                                                      void* __restrict__ OUTv,
                                                      const float* __restrict__ RES) {
  const int b = blockIdx.z;
  const int o0 = blockIdx.y * 64;
  const int s0 = blockIdx.x * 64;
  const int t = threadIdx.x;
  const int tx = t & 15, ty = t >> 4;
  __shared__ float Ws[16][64];
  __shared__ float Xs[16][64];
  float acc[4][4] = {};

  const int wrow = t & 63;
  const int wk0 = (t >> 6) * 4;
  const int xk = t >> 4;
  const int xs0 = (t & 15) * 4;
  const float* Xb = X + (size_t)b * CIN * S;

  for (int c0 = 0; c0 < CIN; c0 += 16) {
    __syncthreads();
    float4 wv = *(const float4*)&W[(size_t)(o0 + wrow) * CIN + c0 + wk0];
    Ws[wk0 + 0][wrow] = wv.x;
    Ws[wk0 + 1][wrow] = wv.y;
    Ws[wk0 + 2][wrow] = wv.z;
    Ws[wk0 + 3][wrow] = wv.w;
    *(float4*)&Xs[xk][xs0] = *(const float4*)&Xb[(size_t)(c0 + xk) * S + s0 + xs0];
    __syncthreads();
    #pragma unroll
    for (int kk = 0; kk < 16; kk++) {
      float4 a = *(const float4*)&Ws[kk][ty * 4];
      float4 xv = *(const float4*)&Xs[kk][tx * 4];
      acc[0][0] += a.x * xv.x; acc[0][1] += a.x * xv.y; acc[0][2] += a.x * xv.z; acc[0][3] += a.x * xv.w;
      acc[1][0] += a.y * xv.x; acc[1][1] += a.y * xv.y; acc[1][2] += a.y * xv.z; acc[1][3] += a.y * xv.w;
      acc[2][0] += a.z * xv.x; acc[2][1] += a.z * xv.y; acc[2][2] += a.z * xv.z; acc[2][3] += a.z * xv.w;
      acc[3][0] += a.w * xv.x; acc[3][1] += a.w * xv.y; acc[3][2] += a.w * xv.z; acc[3][3] += a.w * xv.w;
    }
  }
  #pragma unroll
  for (int i = 0; i < 4; i++) {
    const size_t idx = ((size_t)b * OC + o0 + ty * 4 + i) * S + s0 + tx * 4;
    if (MODE == 0) {
      ushort4 o;
      o.x = f2bf(acc[i][0]); o.y = f2bf(acc[i][1]);
      o.z = f2bf(acc[i][2]); o.w = f2bf(acc[i][3]);
      *(ushort4*)&((ushort*)OUTv)[idx] = o;
    } else {
      const float4 xr = *(const float4*)&RES[idx];
      const float tc = 0.3f, om = 0.7f, inv = 1.3130643285972254f;
      float4 r;
      r.x = (om * xr.x + tc * acc[i][0]) * inv;
      r.y = (om * xr.y + tc * acc[i][1]) * inv;
      r.z = (om * xr.z + tc * acc[i][2]) * inv;
      r.w = (om * xr.w + tc * acc[i][3]) * inv;
      *(float4*)&((float*)OUTv)[idx] = r;
    }
  }
}

// ---------------- pixel norm over 32-channel head groups + transpose ----------
// Reads bf16 qkv [b][768][S]. Groups 0-7: Q head -> Qt[bh][s][d]; 8-15: K head
// -> Kt[bh][s][d]; 16-23: V head -> normalized in place (stays [d][s]).
// grid (S/256, 24, B), block 256.
__global__ __launch_bounds__(256) void pixnorm_kernel(ushort* __restrict__ qkvb,
                                                      ushort* __restrict__ Qt,
                                                      ushort* __restrict__ Kt) {
  const int b = blockIdx.z, g = blockIdx.y;
  const int s = blockIdx.x * 256 + threadIdx.x;
  const size_t base = ((size_t)b * C3 + g * HD) * S + s;
  float v[HD];
  float ss = 0.f;
  #pragma unroll
  for (int d = 0; d < HD; d++) {
    float f = bf2f(qkvb[base + (size_t)d * S]);
    v[d] = f;
    ss += f * f;
  }
  const float r = rsqrtf(ss * (1.0f / HD) + EPS);
  if (g < 16) {
    const int h = g & 7;
    ushort* dst = (g < 8 ? Qt : Kt) + ((size_t)(b * NH + h) * S + s) * HD;
    ushort out[HD];
    #pragma unroll
    for (int d = 0; d < HD; d++) out[d] = f2bf(v[d] * r);
    #pragma unroll
    for (int i = 0; i < 8; i++) *(ushort4*)&dst[i * 4] = *(const ushort4*)&out[i * 4];
  } else {
    #pragma unroll
    for (int d = 0; d < HD; d++) qkvb[base + (size_t)d * S] = f2bf(v[d] * r);
  }
}

// ---------------- MFMA attention -------------------------------------------
// Per wave: 32 queries, loop 64-key tiles. S^T = K.Q^T via mfma_16x16x32_bf16
// (A=K [key][dim] from Kt, B=Q^T from Qt; C: col=query, row=key). exp in fp32,
// l per-lane (col=query). P packed bf16 -> per-wave LDS [q][key] via b64
// writes (4 consecutive keys = C rows quad*4+reg). PV as out^T = V^T.P^T
// (A=V^T from native [dim][key] V, B=P^T read b128 from LDS). No barriers.
// grid (S/128, NH, B), block 256 (4 waves).
__global__ __launch_bounds__(256) void attn_kernel(const ushort* __restrict__ Qt,
                                                   const ushort* __restrict__ Kt,
                                                   const ushort* __restrict__ qkvb,
                                                   float* __restrict__ y) {
  const int b = blockIdx.z, h = blockIdx.y;
  const int wid = threadIdx.x >> 6, lane = threadIdx.x & 63;
  const int col = lane & 15, quad = lane >> 4;
  const int q0 = blockIdx.x * 128 + wid * 32;

  __shared__ ushort P_lds[4][32][72];
  ushort(*__restrict__ P)[72] = P_lds[wid];

  const ushort* Qh = Qt + (size_t)(b * NH + h) * S * HD;
  const ushort* Kh = Kt + (size_t)(b * NH + h) * S * HD;
  const ushort* Vh = qkvb + ((size_t)b * C3 + 2 * CIN + h * HD) * S;

  bf16x8 qf[2];
  #pragma unroll
  for (int nt = 0; nt < 2; nt++)
    qf[nt] = *(const bf16x8*)&Qh[(size_t)(q0 + nt * 16 + col) * HD + quad * 8];

  f32x4 acc[2][2] = {};
  float l[2] = {0.f, 0.f};
  const float sc = 0.17677669529663687f;  // 1/sqrt(32)

  bf16x8 kf[4];
  #pragma unroll
  for (int mt = 0; mt < 4; mt++)
    kf[mt] = *(const bf16x8*)&Kh[(size_t)(mt * 16 + col) * HD + quad * 8];

  for (int kt = 0; kt < S; kt += 64) {
    bf16x8 kcur[4];
    #pragma unroll
    for (int mt = 0; mt < 4; mt++) kcur[mt] = kf[mt];
    if (kt + 64 < S) {
      #pragma unroll
      for (int mt = 0; mt < 4; mt++)
        kf[mt] = *(const bf16x8*)&Kh[(size_t)(kt + 64 + mt * 16 + col) * HD + quad * 8];
    }
    bf16x8 vf[2][2];
    #pragma unroll
    for (int dt = 0; dt < 2; dt++)
      #pragma unroll
      for (int kc = 0; kc < 2; kc++)
        vf[dt][kc] = *(const bf16x8*)&Vh[(size_t)(dt * 16 + col) * S + kt + kc * 32 + quad * 8];

    // scores (transposed) + exp + pack P
    #pragma unroll
    for (int mt = 0; mt < 4; mt++) {
      #pragma unroll
      for (int nt = 0; nt < 2; nt++) {
        f32x4 z = {0.f, 0.f, 0.f, 0.f};
        f32x4 s = __builtin_amdgcn_mfma_f32_16x16x32_bf16(kcur[mt], qf[nt], z, 0, 0, 0);
        float p0 = __expf(s[0] * sc);
        float p1 = __expf(s[1] * sc);
        float p2 = __expf(s[2] * sc);
        float p3 = __expf(s[3] * sc);
        l[nt] += (p0 + p1) + (p2 + p3);
        ushort4 pk;
        pk.x = f2bf(p0); pk.y = f2bf(p1); pk.z = f2bf(p2); pk.w = f2bf(p3);
        *(ushort4*)&P[nt * 16 + col][mt * 16 + quad * 4] = pk;
      }
    }

    // PV: out^T += V^T . P^T
    #pragma unroll
    for (int nt = 0; nt < 2; nt++)
      #pragma unroll
      for (int kc = 0; kc < 2; kc++) {
        bf16x8 pf = *(const bf16x8*)&P[nt * 16 + col][kc * 32 + quad * 8];
        #pragma unroll
        for (int dt = 0; dt < 2; dt++)
          acc[dt][nt] = __builtin_amdgcn_mfma_f32_16x16x32_bf16(vf[dt][kc], pf, acc[dt][nt], 0, 0, 0);
      }
  }

  float invl[2];
  #pragma unroll
  for (int nt = 0; nt < 2; nt++) {
    float t = l[nt];
    t += __shfl_xor(t, 16, 64);
    t += __shfl_xor(t, 32, 64);
    invl[nt] = 1.0f / t;
  }

  float* Yb = y + (size_t)b * CIN * S;
  #pragma unroll
  for (int dt = 0; dt < 2; dt++)
    #pragma unroll
    for (int nt = 0; nt < 2; nt++)
      #pragma unroll
      for (int r = 0; r < 4; r++)
        Yb[(size_t)(h * HD + dt * 16 + quad * 4 + r) * S + q0 + nt * 16 + col] =
            acc[dt][nt][r] * invl[nt];
}

// ---------------- launch ----------------
extern "C" void kernel_launch(void* const* d_in, const int* in_sizes, int n_in,
                              void* d_out, int out_size, void* d_ws, size_t ws_size,
                              hipStream_t stream) {
  const float* x = (const float*)d_in[0];
  const float* w_qkv = (const float*)d_in[1];
  const float* w_out = (const float*)d_in[2];
  float* out = (float*)d_out;

  float* wq_hat = (float*)d_ws;                          // 768*256 f
  float* wo_hat = wq_hat + (size_t)C3 * CIN;             // 256*256 f
  ushort* qkvb = (ushort*)(wo_hat + (size_t)CIN * CIN);  // 2*768*4096 bf16
  ushort* Qt = qkvb + (size_t)2 * C3 * S;                // 2*8*4096*32 bf16
  ushort* Kt = Qt + (size_t)2 * NH * S * HD;             // same
  float* ybuf = (float*)(Kt + (size_t)2 * NH * S * HD);  // 2*256*4096 f

  wnorm_kernel<<<C3 / 4, 256, 0, stream>>>(w_qkv, wq_hat);
  wnorm_kernel<<<CIN / 4, 256, 0, stream>>>(w_out, wo_hat);
  conv1x1_kernel<C3, 0><<<dim3(S / 64, C3 / 64, 2), 256, 0, stream>>>(wq_hat, x, qkvb, nullptr);
  pixnorm_kernel<<<dim3(S / 256, C3 / HD, 2), 256, 0, stream>>>(qkvb, Qt, Kt);
  attn_kernel<<<dim3(S / 128, NH, 2), 256, 0, stream>>>(Qt, Kt, qkvb, ybuf);
  conv1x1_kernel<CIN, 1><<<dim3(S / 64, CIN / 64, 2), 256, 0, stream>>>(wo_hat, ybuf, out, x);
}

// Round 4
// 207.455 us; speedup vs baseline: 9.6852x; 1.1026x over previous
//
#include <hip/hip_runtime.h>
#include <hip/hip_bf16.h>
#include <math.h>

#define S 4096
#define CIN 256
#define C3 768
#define NH 8
#define HD 32

static constexpr float EPS = 1e-4f;

typedef __attribute__((ext_vector_type(8))) __bf16 bf16x8;
typedef __attribute__((ext_vector_type(4))) float f32x4;
typedef __attribute__((ext_vector_type(8))) unsigned short u16x8;

static inline __device__ ushort f2bf(float f) {  // RN-even
  unsigned u = __float_as_uint(f);
  return (ushort)((u + 0x7fffu + ((u >> 16) & 1u)) >> 16);
}
static inline __device__ float bf2f(ushort u) {
  return __uint_as_float(((unsigned)u) << 16);
}
// pack two positive floats to bf16x2 (round-by-add, 3 VALU ops total)
static inline __device__ unsigned pack2bf(float lo, float hi) {
  unsigned a = __float_as_uint(lo) + 0x8000u;
  unsigned b = __float_as_uint(hi) + 0x8000u;
  return __builtin_amdgcn_perm(b, a, 0x07060302);
}

// ---------------- weight norm -> bf16: W_eff = w / (||row|| + 16*EPS) --------
__global__ __launch_bounds__(256) void wnorm_kernel(const float* __restrict__ w,
                                                    ushort* __restrict__ wh) {
  const int row = blockIdx.x * 4 + (threadIdx.x >> 6);
  const int lane = threadIdx.x & 63;
  const float* wr = w + (size_t)row * CIN;
  float v0 = wr[lane], v1 = wr[lane + 64], v2 = wr[lane + 128], v3 = wr[lane + 192];
  float ss = v0 * v0 + v1 * v1 + v2 * v2 + v3 * v3;
  #pragma unroll
  for (int off = 32; off > 0; off >>= 1) ss += __shfl_down(ss, off, 64);
  ss = __shfl(ss, 0, 64);
  const float scale = 1.0f / (sqrtf(ss) + 16.0f * EPS);
  ushort* whr = wh + (size_t)row * CIN;
  whr[lane] = f2bf(v0 * scale);
  whr[lane + 64] = f2bf(v1 * scale);
  whr[lane + 128] = f2bf(v2 * scale);
  whr[lane + 192] = f2bf(v3 * scale);
}

// ---------------- X [b][c][s] fp32 -> Xt [b][s][c] bf16 ----------------------
// 64x64 tiles via LDS; coalesced loads and stores. grid (S/64, CIN/64, B).
__global__ __launch_bounds__(256) void xt_kernel(const float* __restrict__ X,
                                                 ushort* __restrict__ Xt) {
  const int b = blockIdx.z;
  const int s0 = blockIdx.x * 64, c0 = blockIdx.y * 64;
  __shared__ ushort T[64][72];
  const int tc = threadIdx.x >> 4;  // 0..15
  const int ts = threadIdx.x & 15;
  #pragma unroll
  for (int i = 0; i < 4; i++) {
    const float4 v = *(const float4*)&X[((size_t)(b * CIN + c0 + tc + 16 * i)) * S + s0 + ts * 4];
    ushort4 u;
    u.x = f2bf(v.x); u.y = f2bf(v.y); u.z = f2bf(v.z); u.w = f2bf(v.w);
    *(ushort4*)&T[tc + 16 * i][ts * 4] = u;
  }
  __syncthreads();
  #pragma unroll
  for (int i = 0; i < 4; i++) {
    const int sr = tc + 16 * i;
    ushort4 u;
    u.x = T[ts * 4 + 0][sr];
    u.y = T[ts * 4 + 1][sr];
    u.z = T[ts * 4 + 2][sr];
    u.w = T[ts * 4 + 3][sr];
    *(ushort4*)&Xt[((size_t)b * S + s0 + sr) * CIN + c0 + ts * 4] = u;
  }
}

// ---------------- MFMA 1x1 conv: OUT[m][n] = sum_k W[m][k] B[n][k] -----------
// W bf16 [MOUT][256] row-major; Bm bf16 [b][S][256] row-major (k contiguous).
// Direct-from-global fragments, no LDS. Block = 4 waves, tile M=64 x N=128.
// MODE 0: OUT = bf16 [b][S][MOUT] (n-major).  MODE 1: fp32 [b][MOUT][S] + mp_add.
template <int MOUT, int MODE>
__global__ __launch_bounds__(256) void conv_mfma_kernel(const ushort* __restrict__ W,
                                                        const ushort* __restrict__ Bm,
                                                        void* __restrict__ OUTv,
                                                        const float* __restrict__ RES) {
  const int b = blockIdx.z;
  const int wid = threadIdx.x >> 6, lane = threadIdx.x & 63;
  const int col = lane & 15, quad = lane >> 4;
  const int m0 = blockIdx.y * 64 + (wid >> 1) * 32;
  const int n0 = blockIdx.x * 128 + (wid & 1) * 64;
  const ushort* Bb = Bm + (size_t)b * S * CIN;
  f32x4 acc[2][4] = {};
  #pragma unroll
  for (int k0 = 0; k0 < CIN; k0 += 32) {
    bf16x8 af[2], bf[4];
    #pragma unroll
    for (int mi = 0; mi < 2; mi++)
      af[mi] = *(const bf16x8*)&W[(size_t)(m0 + mi * 16 + col) * CIN + k0 + quad * 8];
    #pragma unroll
    for (int ni = 0; ni < 4; ni++)
      bf[ni] = *(const bf16x8*)&Bb[(size_t)(n0 + ni * 16 + col) * CIN + k0 + quad * 8];
    #pragma unroll
    for (int mi = 0; mi < 2; mi++)
      #pragma unroll
      for (int ni = 0; ni < 4; ni++)
        acc[mi][ni] = __builtin_amdgcn_mfma_f32_16x16x32_bf16(af[mi], bf[ni], acc[mi][ni], 0, 0, 0);
  }
  if (MODE == 0) {
    ushort* O = (ushort*)OUTv;
    #pragma unroll
    for (int mi = 0; mi < 2; mi++)
      #pragma unroll
      for (int ni = 0; ni < 4; ni++) {
        ushort4 u;
        u.x = f2bf(acc[mi][ni][0]);
        u.y = f2bf(acc[mi][ni][1]);
        u.z = f2bf(acc[mi][ni][2]);
        u.w = f2bf(acc[mi][ni][3]);
        *(ushort4*)&O[((size_t)b * S + n0 + ni * 16 + col) * MOUT + m0 + mi * 16 + quad * 4] = u;
      }
  } else {
    float* O = (float*)OUTv;
    const float tc = 0.3f, om = 0.7f, inv = 1.3130643285972254f;
    #pragma unroll
    for (int mi = 0; mi < 2; mi++)
      #pragma unroll
      for (int ni = 0; ni < 4; ni++)
        #pragma unroll
        for (int r = 0; r < 4; r++) {
          const size_t idx = ((size_t)(b * MOUT + m0 + mi * 16 + quad * 4 + r)) * S + n0 + ni * 16 + col;
          O[idx] = (om * RES[idx] + tc * acc[mi][ni][r]) * inv;
        }
  }
}

// ---------------- pixel norm (head groups of 32) + layout fan-out ------------
// qkvT [b][s][768] bf16. g<8: Q head -> Qn[bh][s][32]; 8..15: K -> Kn;
// 16..23: V -> Vt[b][h][d][S] (d-major for attention A-fragments).
__global__ __launch_bounds__(256) void pixnorm_kernel(const ushort* __restrict__ qkvT,
                                                      ushort* __restrict__ Qn,
                                                      ushort* __restrict__ Kn,
                                                      ushort* __restrict__ Vt) {
  const int b = blockIdx.z, g = blockIdx.y;
  const int s = blockIdx.x * 256 + threadIdx.x;
  const ushort* src = qkvT + ((size_t)b * S + s) * C3 + g * HD;
  float v[HD];
  float ss = 0.f;
  #pragma unroll
  for (int i = 0; i < 8; i++) {
    ushort4 u = *(const ushort4*)&src[i * 4];
    float f0 = bf2f(u.x), f1 = bf2f(u.y), f2 = bf2f(u.z), f3 = bf2f(u.w);
    v[i * 4 + 0] = f0; v[i * 4 + 1] = f1; v[i * 4 + 2] = f2; v[i * 4 + 3] = f3;
    ss += f0 * f0 + f1 * f1 + f2 * f2 + f3 * f3;
  }
  const float r = rsqrtf(ss * (1.0f / HD) + EPS);
  if (g < 16) {
    ushort* dst = (g < 8 ? Qn : Kn) + ((size_t)(b * NH + (g & 7)) * S + s) * HD;
    #pragma unroll
    for (int i = 0; i < 8; i++) {
      ushort4 u;
      u.x = f2bf(v[i * 4 + 0] * r);
      u.y = f2bf(v[i * 4 + 1] * r);
      u.z = f2bf(v[i * 4 + 2] * r);
      u.w = f2bf(v[i * 4 + 3] * r);
      *(ushort4*)&dst[i * 4] = u;
    }
  } else {
    ushort* dst = Vt + ((size_t)(b * NH + (g - 16)) * HD) * S + s;
    #pragma unroll
    for (int d = 0; d < HD; d++) dst[(size_t)d * S] = f2bf(v[d] * r);
  }
}

// ---------------- MFMA attention with K-split x2 -----------------------------
// Per wave: 32 queries x 2048 keys (one partition). S^T = K.Q^T; exp via
// exp2(s*log2e/sqrt32); P packed to bf16 via v_perm; l via ones-A MFMA;
// PV as out^T = V^T.P^T through per-wave LDS (no barriers anywhere).
// Partials (unnormalized acc fp32, l fp32) to accP/lP.
// grid (S/128, NH*2, B), block 256.
__global__ __launch_bounds__(256, 4) void attn_kernel(const ushort* __restrict__ Qn,
                                                      const ushort* __restrict__ Kn,
                                                      const ushort* __restrict__ Vt,
                                                      float* __restrict__ accP,
                                                      float* __restrict__ lP) {
  const int b = blockIdx.z;
  const int h = blockIdx.y & 7, kp = blockIdx.y >> 3;
  const int wid = threadIdx.x >> 6, lane = threadIdx.x & 63;
  const int col = lane & 15, quad = lane >> 4;
  const int q0 = blockIdx.x * 128 + wid * 32;

  __shared__ ushort P_lds[4][32][72];
  ushort(*__restrict__ P)[72] = P_lds[wid];

  const ushort* Qh = Qn + (size_t)(b * NH + h) * S * HD;
  const ushort* Kh = Kn + (size_t)(b * NH + h) * S * HD;
  const ushort* Vh = Vt + (size_t)(b * NH + h) * HD * S;

  bf16x8 qf[2];
  #pragma unroll
  for (int nt = 0; nt < 2; nt++)
    qf[nt] = *(const bf16x8*)&Qh[(size_t)(q0 + nt * 16 + col) * HD + quad * 8];

  const u16x8 ou = {0x3F80, 0x3F80, 0x3F80, 0x3F80, 0x3F80, 0x3F80, 0x3F80, 0x3F80};
  const bf16x8 ones = __builtin_bit_cast(bf16x8, ou);

  f32x4 acc[2][2] = {};
  f32x4 accl[2] = {};
  const float c = 0.2550348190698169f;  // log2(e)/sqrt(32)

  const int kt0 = kp * (S / 2), kt1 = kt0 + S / 2;
  bf16x8 kf[4];
  #pragma unroll
  for (int mt = 0; mt < 4; mt++)
    kf[mt] = *(const bf16x8*)&Kh[(size_t)(kt0 + mt * 16 + col) * HD + quad * 8];

  for (int kt = kt0; kt < kt1; kt += 64) {
    bf16x8 vf[2][2];
    #pragma unroll
    for (int dt = 0; dt < 2; dt++)
      #pragma unroll
      for (int kc = 0; kc < 2; kc++)
        vf[dt][kc] = *(const bf16x8*)&Vh[(size_t)(dt * 16 + col) * S + kt + kc * 32 + quad * 8];

    #pragma unroll
    for (int mt = 0; mt < 4; mt++) {
      const f32x4 z = {0.f, 0.f, 0.f, 0.f};
      f32x4 s0 = __builtin_amdgcn_mfma_f32_16x16x32_bf16(kf[mt], qf[0], z, 0, 0, 0);
      f32x4 s1 = __builtin_amdgcn_mfma_f32_16x16x32_bf16(kf[mt], qf[1], z, 0, 0, 0);
      // prefetch next tile's K fragment (reads past partition end are still
      // inside the workspace -> harmless garbage, never used on last iter)
      kf[mt] = *(const bf16x8*)&Kh[(size_t)(kt + 64 + mt * 16 + col) * HD + quad * 8];
      uint2 w0, w1;
      w0.x = pack2bf(__builtin_amdgcn_exp2f(s0[0] * c), __builtin_amdgcn_exp2f(s0[1] * c));
      w0.y = pack2bf(__builtin_amdgcn_exp2f(s0[2] * c), __builtin_amdgcn_exp2f(s0[3] * c));
      w1.x = pack2bf(__builtin_amdgcn_exp2f(s1[0] * c), __builtin_amdgcn_exp2f(s1[1] * c));
      w1.y = pack2bf(__builtin_amdgcn_exp2f(s1[2] * c), __builtin_amdgcn_exp2f(s1[3] * c));
      *(uint2*)&P[col][mt * 16 + quad * 4] = w0;
      *(uint2*)&P[16 + col][mt * 16 + quad * 4] = w1;
    }

    #pragma unroll
    for (int nt = 0; nt < 2; nt++)
      #pragma unroll
      for (int kc = 0; kc < 2; kc++) {
        bf16x8 pf = *(const bf16x8*)&P[nt * 16 + col][kc * 32 + quad * 8];
        accl[nt] = __builtin_amdgcn_mfma_f32_16x16x32_bf16(ones, pf, accl[nt], 0, 0, 0);
        #pragma unroll
        for (int dt = 0; dt < 2; dt++)
          acc[dt][nt] = __builtin_amdgcn_mfma_f32_16x16x32_bf16(vf[dt][kc], pf, acc[dt][nt], 0, 0, 0);
      }
  }

  float* ap = accP + ((size_t)((kp * 2 + b) * NH + h)) * S * HD;
  #pragma unroll
  for (int dt = 0; dt < 2; dt++)
    #pragma unroll
    for (int nt = 0; nt < 2; nt++) {
      float4 u;
      u.x = acc[dt][nt][0];
      u.y = acc[dt][nt][1];
      u.z = acc[dt][nt][2];
      u.w = acc[dt][nt][3];
      *(float4*)&ap[(size_t)(q0 + nt * 16 + col) * HD + dt * 16 + quad * 4] = u;
    }
  if (quad == 0) {
    #pragma unroll
    for (int nt = 0; nt < 2; nt++)
      lP[((size_t)((kp * 2 + b) * NH + h)) * S + q0 + nt * 16 + col] = accl[nt][0];
  }
}

// ---------------- combine K-split partials -> Yt [b][s][256] bf16 ------------
// one thread per (b,h,q,dg): 2*8*4096*8 = 524288 threads = 2048 blocks.
__global__ __launch_bounds__(256) void combine_kernel(const float* __restrict__ accP,
                                                      const float* __restrict__ lP,
                                                      ushort* __restrict__ Yt) {
  const int tid = blockIdx.x * 256 + threadIdx.x;
  const int dg = tid & 7;
  const int q = (tid >> 3) & (S - 1);
  const int h = (tid >> 15) & 7;
  const int b = tid >> 18;
  const size_t i0 = ((size_t)(b * NH + h)) * S + q;
  const size_t part = (size_t)2 * NH * S;
  const float4 a0 = *(const float4*)&accP[i0 * HD + dg * 4];
  const float4 a1 = *(const float4*)&accP[(part * HD) + i0 * HD + dg * 4];
  const float rl = 1.0f / (lP[i0] + lP[part + i0]);
  ushort4 o;
  o.x = f2bf((a0.x + a1.x) * rl);
  o.y = f2bf((a0.y + a1.y) * rl);
  o.z = f2bf((a0.z + a1.z) * rl);
  o.w = f2bf((a0.w + a1.w) * rl);
  *(ushort4*)&Yt[((size_t)b * S + q) * CIN + h * HD + dg * 4] = o;
}

// ---------------- launch ----------------
extern "C" void kernel_launch(void* const* d_in, const int* in_sizes, int n_in,
                              void* d_out, int out_size, void* d_ws, size_t ws_size,
                              hipStream_t stream) {
  const float* x = (const float*)d_in[0];
  const float* w_qkv = (const float*)d_in[1];
  const float* w_out = (const float*)d_in[2];
  float* out = (float*)d_out;

  ushort* p = (ushort*)d_ws;
  ushort* wqb = p; p += (size_t)C3 * CIN;       // 196608
  ushort* wob = p; p += (size_t)CIN * CIN;      // 65536
  ushort* Qn = p; p += (size_t)2 * NH * S * HD; // 2097152
  ushort* Kn = p; p += (size_t)2 * NH * S * HD;
  ushort* Vt = p; p += (size_t)2 * NH * S * HD;
  ushort* Yt = p; p += (size_t)2 * S * CIN;
  // Region R: Xt (4 MB) + qkvT (12.6 MB) die after pixnorm; accP fp32
  // (2*2*8*4096*32 floats = 16.78 MB) aliases the same 16.78 MB exactly.
  ushort* R = p; p += (size_t)2 * S * CIN + (size_t)2 * S * C3;
  ushort* Xt = R;
  ushort* qkvT = R + (size_t)2 * S * CIN;
  float* accP = (float*)R;
  float* lP = (float*)p;                         // 2*2*8*4096 floats

  wnorm_kernel<<<C3 / 4, 256, 0, stream>>>(w_qkv, wqb);
  wnorm_kernel<<<CIN / 4, 256, 0, stream>>>(w_out, wob);
  xt_kernel<<<dim3(S / 64, CIN / 64, 2), 256, 0, stream>>>(x, Xt);
  conv_mfma_kernel<C3, 0><<<dim3(S / 128, C3 / 64, 2), 256, 0, stream>>>(wqb, Xt, qkvT, nullptr);
  pixnorm_kernel<<<dim3(S / 256, 24, 2), 256, 0, stream>>>(qkvT, Qn, Kn, Vt);
  attn_kernel<<<dim3(S / 128, NH * 2, 2), 256, 0, stream>>>(Qn, Kn, Vt, accP, lP);
  combine_kernel<<<2048, 256, 0, stream>>>(accP, lP, Yt);
  conv_mfma_kernel<CIN, 1><<<dim3(S / 128, CIN / 64, 2), 256, 0, stream>>>(wob, Yt, out, x);
}